// Round 15
// baseline (48.864 us; speedup 1.0000x reference)
//
#include <hip/hip_runtime.h>

#define BATCH   65536
#define IN_DIM  784
#define HDIM    20
#define NCLS    10
#define THREADS 256           // 4 waves/block
#define SPW     16
#define SPB     64
#define NFULL   24            // staged 32-wide K-steps; step 24 = direct 16-wide tail
#define NWROWS  48            // compacted weight rows (40 active + 8 zero)

// d_ws layout (bytes)
#define OFF_WHC  0            // fp16 Whc[48][784]   = 75264
#define OFF_W2C  76800        // fp16 W2c[48][32]    = 3072
#define OFF_W3C  79872        // fp16 W3c[48][32]    = 3072
#define OFF_WLC  82944        // fp16 Wlc[16][32]    = 1024
#define OFF_BC   83968        // fp32 bc[3][2][24]   = 576
#define OFF_BLC  84544        // fp32 blc[16]        = 64

// LDS map: A[3 bufs][64 rows][128B] = 24576 at 0; preLds[4][16][44] f32 = 11264 at 24576
#define PRE_OFF  24576
#define WAITVM(N) asm volatile("s_waitcnt vmcnt(" #N ")" ::: "memory")

typedef __attribute__((ext_vector_type(2))) __fp16   fp16x2;
typedef __attribute__((ext_vector_type(8))) _Float16 f16x8;
typedef __attribute__((ext_vector_type(4))) float    f32x4;
typedef __attribute__((ext_vector_type(4))) unsigned u32x4;

typedef union { uint4 q; f16x8 v; } BFrag;
typedef union { fp16x2 h[4]; f16x8 v; } AFrag;
typedef union { fp16x2 h[2]; uint2 u; } Pack4;
typedef union { u32x4 u; float f[4]; } AU;
typedef union { u32x4 u; f16x8 v; } BU;

__device__ __forceinline__ void gld16(const void* g, void* l) {
    __builtin_amdgcn_global_load_lds(
        (const __attribute__((address_space(1))) unsigned int*)g,
        (__attribute__((address_space(3))) unsigned int*)l, 16, 0, 0);
}

// asm 16B global load -> register, consumed only after a counted vmcnt wait
#define GLOAD(dst, p) \
    asm volatile("global_load_dwordx4 %0, %1, off" : "=&v"(dst) : "v"(p))

// sorted(set(row))[:2] -> (e0, e1, mask)
__device__ __forceinline__ void route(const int* pw, bool is64, int row,
                                      int& e0, int& e1, float& m) {
    int v0, v1, v2;
    if (is64) {
        v0 = pw[(row * 3 + 0) * 2];
        v1 = pw[(row * 3 + 1) * 2];
        v2 = pw[(row * 3 + 2) * 2];
    } else {
        v0 = pw[row * 3 + 0];
        v1 = pw[row * 3 + 1];
        v2 = pw[row * 3 + 2];
    }
    int lo  = min(v0, min(v1, v2));
    int hi  = max(v0, max(v1, v2));
    int mid = v0 + v1 + v2 - lo - hi;
    e0 = lo;
    if (mid != lo)     { e1 = mid; m = 1.0f; }
    else if (hi != lo) { e1 = hi;  m = 1.0f; }
    else               { e1 = lo;  m = 0.0f; }
}

// ---- pre-kernel 1: compact active W1 rows -> fp16 Whc[48][784]; rows>=40 zero
__global__ __launch_bounds__(256)
void cvt_w1_kernel(const float* __restrict__ W1, const int* __restrict__ pathway,
                   char* __restrict__ ws) {
    _Float16* Whc = (_Float16*)(ws + OFF_WHC);
    const int gid = blockIdx.x * 256 + threadIdx.x;
    if (gid >= NWROWS * (IN_DIM / 8)) return;
    const int u  = gid / (IN_DIM / 8);
    const int k8 = gid % (IN_DIM / 8);

    bool is64 = ((pathway[1] | pathway[3] | pathway[5] | pathway[7]) == 0);
    int e10, e11; float m1;
    route(pathway, is64, 0, e10, e11, m1);

    uint4 outw = make_uint4(0, 0, 0, 0);
    if (u < 2 * HDIM) {
        const int e = (u < HDIM) ? e10 : e11;
        const int o = (u < HDIM) ? u : u - HDIM;
        const float* src = W1 + ((size_t)e * HDIM + o) * IN_DIM + k8 * 8;
        const float4 v0 = *reinterpret_cast<const float4*>(src);
        const float4 v1 = *reinterpret_cast<const float4*>(src + 4);
        Pack4 p0, p1;
        p0.h[0] = __builtin_amdgcn_cvt_pkrtz(v0.x, v0.y);
        p0.h[1] = __builtin_amdgcn_cvt_pkrtz(v0.z, v0.w);
        p1.h[0] = __builtin_amdgcn_cvt_pkrtz(v1.x, v1.y);
        p1.h[1] = __builtin_amdgcn_cvt_pkrtz(v1.z, v1.w);
        outw = make_uint4(p0.u.x, p0.u.y, p1.u.x, p1.u.y);
    }
    *reinterpret_cast<uint4*>(Whc + (size_t)u * IN_DIM + k8 * 8) = outw;
}

// ---- pre-kernel 2: compact W2/W3/Wl (fp16, K pad 32) + biases (fp32) ----
__global__ __launch_bounds__(256)
void cvt_small_kernel(const float* __restrict__ W2, const float* __restrict__ W3,
                      const float* __restrict__ Wl, const float* __restrict__ b1,
                      const float* __restrict__ b2, const float* __restrict__ b3,
                      const float* __restrict__ bl, const int* __restrict__ pathway,
                      char* __restrict__ ws) {
    const int gid = blockIdx.x * 256 + threadIdx.x;
    bool is64 = ((pathway[1] | pathway[3] | pathway[5] | pathway[7]) == 0);
    int e10, e11, e20, e21, e30, e31;
    float m1, m2, m3;
    route(pathway, is64, 0, e10, e11, m1);
    route(pathway, is64, 1, e20, e21, m2);
    route(pathway, is64, 2, e30, e31, m3);

    if (gid < 1536) {                               // W2c[48][32]
        const int u = gid >> 5, k = gid & 31;
        float v = 0.0f;
        if (u < 2 * HDIM && k < HDIM) {
            const int e = (u < HDIM) ? e20 : e21;
            const int o = (u < HDIM) ? u : u - HDIM;
            v = W2[((size_t)e * HDIM + o) * HDIM + k];
        }
        ((_Float16*)(ws + OFF_W2C))[gid] = (_Float16)v;
    } else if (gid < 3072) {                        // W3c[48][32]
        const int i = gid - 1536;
        const int u = i >> 5, k = i & 31;
        float v = 0.0f;
        if (u < 2 * HDIM && k < HDIM) {
            const int e = (u < HDIM) ? e30 : e31;
            const int o = (u < HDIM) ? u : u - HDIM;
            v = W3[((size_t)e * HDIM + o) * HDIM + k];
        }
        ((_Float16*)(ws + OFF_W3C))[i] = (_Float16)v;
    } else if (gid < 3584) {                        // Wlc[16][32]
        const int i = gid - 3072;
        const int c = i >> 5, k = i & 31;
        float v = (c < NCLS && k < HDIM) ? Wl[c * HDIM + k] : 0.0f;
        ((_Float16*)(ws + OFF_WLC))[i] = (_Float16)v;
    } else if (gid < 3728) {                        // bc[3][2][24]
        const int i = gid - 3584;
        const int l = i / 48, hb = (i % 48) / 24, c = i % 24;
        float v = 0.0f;
        if (c < HDIM) {
            int e;
            const float* B;
            if (l == 0)      { e = hb ? e11 : e10; B = b1; }
            else if (l == 1) { e = hb ? e21 : e20; B = b2; }
            else             { e = hb ? e31 : e30; B = b3; }
            v = B[e * HDIM + c];
        }
        ((float*)(ws + OFF_BC))[i] = v;
    } else if (gid < 3744) {                        // blc[16]
        const int c = gid - 3728;
        ((float*)(ws + OFF_BLC))[c] = (c < NCLS) ? bl[c] : 0.0f;
    }
}

__global__ __launch_bounds__(THREADS, 4)
void pathnet_kernel(const float* __restrict__ x, const char* __restrict__ ws,
                    const int* __restrict__ pathway, float* __restrict__ out)
{
    __shared__ __align__(16) char smem[PRE_OFF + 11264];   // 35 KB

    const int t    = threadIdx.x;
    const int lane = t & 63;
    const int w    = __builtin_amdgcn_readfirstlane(t >> 6);

    bool is64 = ((pathway[1] | pathway[3] | pathway[5] | pathway[7]) == 0);
    int e10, e11, e20, e21, e30, e31;
    float m1, m2, m3;
    route(pathway, is64, 0, e10, e11, m1);
    route(pathway, is64, 1, e20, e21, m2);
    route(pathway, is64, 2, e30, e31, m3);

    const _Float16* Whc = (const _Float16*)(ws + OFF_WHC);
    const int sbase0 = blockIdx.x * SPB;
    const float* xg = x + (size_t)sbase0 * IN_DIM;

    // ---- per-lane staging geometry (A: wave-private rows, swizzled source) --
    const int srow8 = lane >> 3;                    // sub-row within 8-row group
    const int csw   = (lane & 7) ^ srow8;           // pre-swizzled source chunk
    const float* aSrc0 = xg + (size_t)((w * 2 + 0) * 8 + srow8) * IN_DIM + csw * 4;
    const float* aSrc1 = xg + (size_t)((w * 2 + 1) * 8 + srow8) * IN_DIM + csw * 4;
    char* aDst0 = smem + (w * 2 + 0) * 1024;        // + buf*8192
    char* aDst1 = smem + (w * 2 + 1) * 1024;

    // ---- per-lane read geometry ----
    const int row16 = lane & 15;
    const int kg    = lane >> 4;
    const int arow  = w * 16 + row16;
    const int aoff0 = arow * 128 + (((2 * kg + 0) ^ (arow & 7)) * 16);
    const int aoff1 = arow * 128 + (((2 * kg + 1) ^ (arow & 7)) * 16);

    // ---- B base pointers (registers, L2-hot) ----
    const _Float16* bb0 = Whc + (size_t)(0 * 16 + row16) * IN_DIM + kg * 8;
    const _Float16* bb1 = Whc + (size_t)(1 * 16 + row16) * IN_DIM + kg * 8;
    const _Float16* bb2 = Whc + (size_t)(2 * 16 + row16) * IN_DIM + kg * 8;

    f32x4 acc[3];
#pragma unroll
    for (int tt = 0; tt < 3; ++tt) acc[tt] = (f32x4){0.f, 0.f, 0.f, 0.f};

    u32x4 bS[3][3];                                 // B ring: depth 3, static idx

    // ---- prologue: steps 0,1 in flight (5 VMEM ops per step per wave) ----
    gld16(aSrc0, aDst0);  gld16(aSrc1, aDst1);
    GLOAD(bS[0][0], bb0); GLOAD(bS[0][1], bb1); GLOAD(bS[0][2], bb2);
    gld16(aSrc0 + 32, aDst0 + 8192);  gld16(aSrc1 + 32, aDst1 + 8192);
    GLOAD(bS[1][0], bb0 + 32); GLOAD(bS[1][1], bb1 + 32); GLOAD(bS[1][2], bb2 + 32);

    // ---- barrier-free main loop: per-wave counted vmcnt pipeline ----
#pragma unroll
    for (int i = 0; i < NFULL; ++i) {
        if (i + 2 < NFULL) {
            const int b = (i + 2) % 3;
            gld16(aSrc0 + (i + 2) * 32, aDst0 + b * 8192);
            gld16(aSrc1 + (i + 2) * 32, aDst1 + b * 8192);
            GLOAD(bS[b][0], bb0 + (i + 2) * 32);
            GLOAD(bS[b][1], bb1 + (i + 2) * 32);
            GLOAD(bS[b][2], bb2 + (i + 2) * 32);
        }
        if (i < NFULL - 2)       WAITVM(10);   // steps i+1, i+2 stay in flight
        else if (i == NFULL - 2) WAITVM(5);
        else                     WAITVM(0);

        u32x4 a0, a1;
        const int bo = (i % 3) * 8192;
        asm volatile("ds_read_b128 %0, %1" : "=&v"(a0) : "v"(aoff0 + bo));
        asm volatile("ds_read_b128 %0, %1" : "=&v"(a1) : "v"(aoff1 + bo));
        asm volatile("s_waitcnt lgkmcnt(0)" ::: "memory");
        __builtin_amdgcn_sched_barrier(0);

        AU ua0, ua1;
        ua0.u = a0; ua1.u = a1;
        AFrag af;
        af.h[0] = __builtin_amdgcn_cvt_pkrtz(ua0.f[0], ua0.f[1]);
        af.h[1] = __builtin_amdgcn_cvt_pkrtz(ua0.f[2], ua0.f[3]);
        af.h[2] = __builtin_amdgcn_cvt_pkrtz(ua1.f[0], ua1.f[1]);
        af.h[3] = __builtin_amdgcn_cvt_pkrtz(ua1.f[2], ua1.f[3]);
        BU b0u, b1u, b2u;
        b0u.u = bS[i % 3][0]; b1u.u = bS[i % 3][1]; b2u.u = bS[i % 3][2];
        acc[0] = __builtin_amdgcn_mfma_f32_16x16x32_f16(af.v, b0u.v, acc[0], 0, 0, 0);
        acc[1] = __builtin_amdgcn_mfma_f32_16x16x32_f16(af.v, b1u.v, acc[1], 0, 0, 0);
        acc[2] = __builtin_amdgcn_mfma_f32_16x16x32_f16(af.v, b2u.v, acc[2], 0, 0, 0);
    }

    // ---- direct tail: k in [768, 784), kg 0..1 valid ----
    {
        AFrag af;
        BFrag bf[3];
        if (kg < 2) {
            const float* ap = xg + (size_t)(w * 16 + row16) * IN_DIM + 768 + kg * 8;
            const float4 q0 = *reinterpret_cast<const float4*>(ap);
            const float4 q1 = *reinterpret_cast<const float4*>(ap + 4);
            af.h[0] = __builtin_amdgcn_cvt_pkrtz(q0.x, q0.y);
            af.h[1] = __builtin_amdgcn_cvt_pkrtz(q0.z, q0.w);
            af.h[2] = __builtin_amdgcn_cvt_pkrtz(q1.x, q1.y);
            af.h[3] = __builtin_amdgcn_cvt_pkrtz(q1.z, q1.w);
#pragma unroll
            for (int tt = 0; tt < 3; ++tt) {
                const int u = tt * 16 + row16;
                bf[tt].q = *reinterpret_cast<const uint4*>(Whc + (size_t)u * IN_DIM + 768 + kg * 8);
            }
        } else {
            const fp16x2 z = __builtin_amdgcn_cvt_pkrtz(0.f, 0.f);
            af.h[0] = af.h[1] = af.h[2] = af.h[3] = z;
#pragma unroll
            for (int tt = 0; tt < 3; ++tt) bf[tt].q = make_uint4(0, 0, 0, 0);
        }
#pragma unroll
        for (int tt = 0; tt < 3; ++tt)
            acc[tt] = __builtin_amdgcn_mfma_f32_16x16x32_f16(af.v, bf[tt].v, acc[tt], 0, 0, 0);
    }

    // ================= MFMA epilogue (per-wave private, no barriers) ========
    float* pre = reinterpret_cast<float*>(smem + PRE_OFF) + w * (16 * 44);

#pragma unroll
    for (int tt = 0; tt < 3; ++tt) {
        const int col = tt * 16 + row16;
        if (col < 2 * HDIM) {
#pragma unroll
            for (int r = 0; r < 4; ++r)
                pre[(kg * 4 + r) * 44 + col] = acc[tt][r];
        }
    }

    const _Float16* W2c = (const _Float16*)(ws + OFF_W2C);
    const _Float16* W3c = (const _Float16*)(ws + OFF_W3C);
    const _Float16* Wlc = (const _Float16*)(ws + OFF_WLC);
    const float*    bc  = (const float*)(ws + OFF_BC);
    const float*    blc = (const float*)(ws + OFF_BLC);

    BFrag w2f[3], w3f[3], wlf;
#pragma unroll
    for (int tt = 0; tt < 3; ++tt) {
        const int u = tt * 16 + row16;
        w2f[tt].q = *reinterpret_cast<const uint4*>(W2c + u * 32 + kg * 8);
        w3f[tt].q = *reinterpret_cast<const uint4*>(W3c + u * 32 + kg * 8);
    }
    wlf.q = *reinterpret_cast<const uint4*>(Wlc + row16 * 32 + kg * 8);
    const float blv = blc[row16];

    const float* prow = pre + row16 * 44;

    auto buildA = [&](const float* b0, const float* b1, float mm) -> AFrag {
        AFrag af;
        if (kg == 3) {
            const fp16x2 z = __builtin_amdgcn_cvt_pkrtz(0.f, 0.f);
            af.h[0] = af.h[1] = af.h[2] = af.h[3] = z;
            return af;
        }
        const float* p = prow + kg * 8;
        const float4 p0 = *reinterpret_cast<const float4*>(p);
        const float4 p1 = *reinterpret_cast<const float4*>(p + 4);
        const float4 q0 = *reinterpret_cast<const float4*>(p + 20);
        const float4 q1 = *reinterpret_cast<const float4*>(p + 24);
        const float4 c0 = *reinterpret_cast<const float4*>(b0 + kg * 8);
        const float4 c1 = *reinterpret_cast<const float4*>(b0 + kg * 8 + 4);
        const float4 d0 = *reinterpret_cast<const float4*>(b1 + kg * 8);
        const float4 d1 = *reinterpret_cast<const float4*>(b1 + kg * 8 + 4);
        float h[8];
        h[0] = fmaxf(p0.x + c0.x, 0.f) + mm * fmaxf(q0.x + d0.x, 0.f);
        h[1] = fmaxf(p0.y + c0.y, 0.f) + mm * fmaxf(q0.y + d0.y, 0.f);
        h[2] = fmaxf(p0.z + c0.z, 0.f) + mm * fmaxf(q0.z + d0.z, 0.f);
        h[3] = fmaxf(p0.w + c0.w, 0.f) + mm * fmaxf(q0.w + d0.w, 0.f);
        h[4] = fmaxf(p1.x + c1.x, 0.f) + mm * fmaxf(q1.x + d1.x, 0.f);
        h[5] = fmaxf(p1.y + c1.y, 0.f) + mm * fmaxf(q1.y + d1.y, 0.f);
        h[6] = fmaxf(p1.z + c1.z, 0.f) + mm * fmaxf(q1.z + d1.z, 0.f);
        h[7] = fmaxf(p1.w + c1.w, 0.f) + mm * fmaxf(q1.w + d1.w, 0.f);
        if (kg == 2) { h[4] = h[5] = h[6] = h[7] = 0.f; }
        af.h[0] = __builtin_amdgcn_cvt_pkrtz(h[0], h[1]);
        af.h[1] = __builtin_amdgcn_cvt_pkrtz(h[2], h[3]);
        af.h[2] = __builtin_amdgcn_cvt_pkrtz(h[4], h[5]);
        af.h[3] = __builtin_amdgcn_cvt_pkrtz(h[6], h[7]);
        return af;
    };

    // layer 2
    AFrag a1 = buildA(bc + 0, bc + 24, m1);
    f32x4 acc2[3];
#pragma unroll
    for (int tt = 0; tt < 3; ++tt) {
        acc2[tt] = (f32x4){0.f, 0.f, 0.f, 0.f};
        acc2[tt] = __builtin_amdgcn_mfma_f32_16x16x32_f16(a1.v, w2f[tt].v, acc2[tt], 0, 0, 0);
    }
#pragma unroll
    for (int tt = 0; tt < 3; ++tt) {
        const int col = tt * 16 + row16;
        if (col < 2 * HDIM) {
#pragma unroll
            for (int r = 0; r < 4; ++r)
                pre[(kg * 4 + r) * 44 + col] = acc2[tt][r];
        }
    }

    // layer 3
    AFrag a2 = buildA(bc + 48, bc + 72, m2);
    f32x4 acc3[3];
#pragma unroll
    for (int tt = 0; tt < 3; ++tt) {
        acc3[tt] = (f32x4){0.f, 0.f, 0.f, 0.f};
        acc3[tt] = __builtin_amdgcn_mfma_f32_16x16x32_f16(a2.v, w3f[tt].v, acc3[tt], 0, 0, 0);
    }
#pragma unroll
    for (int tt = 0; tt < 3; ++tt) {
        const int col = tt * 16 + row16;
        if (col < 2 * HDIM) {
#pragma unroll
            for (int r = 0; r < 4; ++r)
                pre[(kg * 4 + r) * 44 + col] = acc3[tt][r];
        }
    }

    // readout
    AFrag a3 = buildA(bc + 96, bc + 120, m3);
    f32x4 accY = (f32x4){0.f, 0.f, 0.f, 0.f};
    accY = __builtin_amdgcn_mfma_f32_16x16x32_f16(a3.v, wlf.v, accY, 0, 0, 0);

    if (row16 < NCLS) {
#pragma unroll
        for (int r = 0; r < 4; ++r) {
            const int srow = sbase0 + w * SPW + kg * 4 + r;
            out[(size_t)srow * NCLS + row16] = accY[r] + blv;
        }
    }
}

extern "C" void kernel_launch(void* const* d_in, const int* in_sizes, int n_in,
                              void* d_out, int out_size, void* d_ws, size_t ws_size,
                              hipStream_t stream) {
    const float* x  = (const float*)d_in[0];
    const float* W1 = (const float*)d_in[1];
    const float* b1 = (const float*)d_in[2];
    const float* W2 = (const float*)d_in[3];
    const float* b2 = (const float*)d_in[4];
    const float* W3 = (const float*)d_in[5];
    const float* b3 = (const float*)d_in[6];
    const float* Wl = (const float*)d_in[7];
    const float* bl = (const float*)d_in[8];
    const int*   pw = (const int*)d_in[9];
    float* out = (float*)d_out;
    char* ws = (char*)d_ws;

    const int nw = NWROWS * (IN_DIM / 8);          // 4704 tasks
    cvt_w1_kernel<<<(nw + 255) / 256, 256, 0, stream>>>(W1, pw, ws);
    cvt_small_kernel<<<15, 256, 0, stream>>>(W2, W3, Wl, b1, b2, b3, bl, pw, ws);

    dim3 grid(BATCH / SPB);   // 1024 blocks = 4 blocks/CU, all resident
    pathnet_kernel<<<grid, THREADS, 0, stream>>>(x, ws, pw, out);
}

// Round 16
// 42.330 us; speedup vs baseline: 1.1544x; 1.1544x over previous
//
#include <hip/hip_runtime.h>

#define BATCH   65536
#define IN_DIM  784
#define HDIM    20
#define NCLS    10
#define THREADS 256           // 4 waves/block
#define SPW     16
#define SPB     64
#define NFULL   24            // staged 32-wide K-steps; step 24 = direct 16-wide tail
#define NWROWS  48            // compacted weight rows (40 active + 8 zero)

// d_ws layout (bytes)
#define OFF_WHC  0            // fp16 Whc[48][784]   = 75264
#define OFF_W2C  76800        // fp16 W2c[48][32]    = 3072
#define OFF_W3C  79872        // fp16 W3c[48][32]    = 3072
#define OFF_WLC  82944        // fp16 Wlc[16][32]    = 1024
#define OFF_BC   83968        // fp32 bc[3][2][24]   = 576
#define OFF_BLC  84544        // fp32 blc[16]        = 64

// LDS map: A[4][64][128B] at 0..32768; B[4][48][64B] at 32768..45056
// epilogue preLds[4 waves][16][44] fp32 (11264 B) aliases A bufs 0-1.
#define ABUF(b)  (smem + (size_t)(b) * 8192)
#define BBUF(b)  (smem + 32768 + (size_t)(b) * 3072)
#define WAITVM(N) asm volatile("s_waitcnt vmcnt(" #N ")" ::: "memory")

typedef __attribute__((ext_vector_type(2))) __fp16   fp16x2;
typedef __attribute__((ext_vector_type(8))) _Float16 f16x8;
typedef __attribute__((ext_vector_type(4))) float    f32x4;
typedef __attribute__((ext_vector_type(4))) unsigned u32x4;

typedef union { uint4 q; f16x8 v; } BFrag;
typedef union { fp16x2 h[4]; f16x8 v; } AFrag;
typedef union { fp16x2 h[2]; uint2 u; } Pack4;
typedef union { u32x4 u; float f[4]; } AU;
typedef union { u32x4 u; f16x8 v; } BU;

__device__ __forceinline__ void gld16(const void* g, void* l) {
    __builtin_amdgcn_global_load_lds(
        (const __attribute__((address_space(1))) unsigned int*)g,
        (__attribute__((address_space(3))) unsigned int*)l, 16, 0, 0);
}

// sorted(set(row))[:2] -> (e0, e1, mask)
__device__ __forceinline__ void route(const int* pw, bool is64, int row,
                                      int& e0, int& e1, float& m) {
    int v0, v1, v2;
    if (is64) {
        v0 = pw[(row * 3 + 0) * 2];
        v1 = pw[(row * 3 + 1) * 2];
        v2 = pw[(row * 3 + 2) * 2];
    } else {
        v0 = pw[row * 3 + 0];
        v1 = pw[row * 3 + 1];
        v2 = pw[row * 3 + 2];
    }
    int lo  = min(v0, min(v1, v2));
    int hi  = max(v0, max(v1, v2));
    int mid = v0 + v1 + v2 - lo - hi;
    e0 = lo;
    if (mid != lo)     { e1 = mid; m = 1.0f; }
    else if (hi != lo) { e1 = hi;  m = 1.0f; }
    else               { e1 = lo;  m = 0.0f; }
}

// ---- merged pre-kernel: Whc compaction (tasks 0..4703) + small weights/biases
// (tasks 4704..8447) in one launch.
__global__ __launch_bounds__(256)
void cvt_all_kernel(const float* __restrict__ W1, const float* __restrict__ W2,
                    const float* __restrict__ W3, const float* __restrict__ Wl,
                    const float* __restrict__ b1, const float* __restrict__ b2,
                    const float* __restrict__ b3, const float* __restrict__ bl,
                    const int* __restrict__ pathway, char* __restrict__ ws) {
    const int gid = blockIdx.x * 256 + threadIdx.x;

    bool is64 = ((pathway[1] | pathway[3] | pathway[5] | pathway[7]) == 0);
    int e10, e11, e20, e21, e30, e31;
    float m1, m2, m3;
    route(pathway, is64, 0, e10, e11, m1);
    route(pathway, is64, 1, e20, e21, m2);
    route(pathway, is64, 2, e30, e31, m3);

    if (gid < NWROWS * (IN_DIM / 8)) {              // Whc[48][784], one uint4 each
        const int u  = gid / (IN_DIM / 8);
        const int k8 = gid % (IN_DIM / 8);
        uint4 outw = make_uint4(0, 0, 0, 0);
        if (u < 2 * HDIM) {
            const int e = (u < HDIM) ? e10 : e11;
            const int o = (u < HDIM) ? u : u - HDIM;
            const float* src = W1 + ((size_t)e * HDIM + o) * IN_DIM + k8 * 8;
            const float4 v0 = *reinterpret_cast<const float4*>(src);
            const float4 v1 = *reinterpret_cast<const float4*>(src + 4);
            Pack4 p0, p1;
            p0.h[0] = __builtin_amdgcn_cvt_pkrtz(v0.x, v0.y);
            p0.h[1] = __builtin_amdgcn_cvt_pkrtz(v0.z, v0.w);
            p1.h[0] = __builtin_amdgcn_cvt_pkrtz(v1.x, v1.y);
            p1.h[1] = __builtin_amdgcn_cvt_pkrtz(v1.z, v1.w);
            outw = make_uint4(p0.u.x, p0.u.y, p1.u.x, p1.u.y);
        }
        *reinterpret_cast<uint4*>((_Float16*)(ws + OFF_WHC) + (size_t)u * IN_DIM + k8 * 8) = outw;
        return;
    }

    const int g2 = gid - NWROWS * (IN_DIM / 8);
    if (g2 < 1536) {                                // W2c[48][32]
        const int u = g2 >> 5, k = g2 & 31;
        float v = 0.0f;
        if (u < 2 * HDIM && k < HDIM) {
            const int e = (u < HDIM) ? e20 : e21;
            const int o = (u < HDIM) ? u : u - HDIM;
            v = W2[((size_t)e * HDIM + o) * HDIM + k];
        }
        ((_Float16*)(ws + OFF_W2C))[g2] = (_Float16)v;
    } else if (g2 < 3072) {                         // W3c[48][32]
        const int i = g2 - 1536;
        const int u = i >> 5, k = i & 31;
        float v = 0.0f;
        if (u < 2 * HDIM && k < HDIM) {
            const int e = (u < HDIM) ? e30 : e31;
            const int o = (u < HDIM) ? u : u - HDIM;
            v = W3[((size_t)e * HDIM + o) * HDIM + k];
        }
        ((_Float16*)(ws + OFF_W3C))[i] = (_Float16)v;
    } else if (g2 < 3584) {                         // Wlc[16][32]
        const int i = g2 - 3072;
        const int c = i >> 5, k = i & 31;
        float v = (c < NCLS && k < HDIM) ? Wl[c * HDIM + k] : 0.0f;
        ((_Float16*)(ws + OFF_WLC))[i] = (_Float16)v;
    } else if (g2 < 3728) {                         // bc[3][2][24]
        const int i = g2 - 3584;
        const int l = i / 48, hb = (i % 48) / 24, c = i % 24;
        float v = 0.0f;
        if (c < HDIM) {
            int e;
            const float* B;
            if (l == 0)      { e = hb ? e11 : e10; B = b1; }
            else if (l == 1) { e = hb ? e21 : e20; B = b2; }
            else             { e = hb ? e31 : e30; B = b3; }
            v = B[e * HDIM + c];
        }
        ((float*)(ws + OFF_BC))[i] = v;
    } else if (g2 < 3744) {                         // blc[16]
        const int c = g2 - 3728;
        ((float*)(ws + OFF_BLC))[c] = (c < NCLS) ? bl[c] : 0.0f;
    }
}

// ---- staging (swizzle, rule #21 both-sides) ----
__device__ __forceinline__ void stageA(char* smem, int buf, int kstep,
                                       const float* __restrict__ xg,
                                       int w, int lane) {
#pragma unroll
    for (int j = 0; j < 2; ++j) {
        const int q    = w * 2 + j;
        const int row  = q * 8 + (lane >> 3);
        const int c    = (lane & 7) ^ (lane >> 3);
        const float* g = xg + (size_t)row * IN_DIM + kstep * 32 + c * 4;
        gld16(g, ABUF(buf) + q * 1024);
    }
}

__device__ __forceinline__ void stageB(char* smem, int buf, int kstep,
                                       const _Float16* __restrict__ Whc,
                                       int w, int lane) {
    if (w < 3) {
        const int row = w * 16 + (lane >> 2);
        const int c   = (lane & 3) ^ ((lane >> 3) & 3);
        const _Float16* g = Whc + (size_t)row * IN_DIM + kstep * 32 + c * 8;
        gld16(g, BBUF(buf) + w * 1024);
    }
}

__device__ __forceinline__ void computeAsm(int a0a, int a1a, int b0a, int b1a,
                                           int b2a, f32x4 acc[3]) {
    u32x4 a0, a1, b0, b1, b2;
    asm volatile("ds_read_b128 %0, %1" : "=v"(a0) : "v"(a0a));
    asm volatile("ds_read_b128 %0, %1" : "=v"(a1) : "v"(a1a));
    asm volatile("ds_read_b128 %0, %1" : "=v"(b0) : "v"(b0a));
    asm volatile("ds_read_b128 %0, %1" : "=v"(b1) : "v"(b1a));
    asm volatile("ds_read_b128 %0, %1" : "=v"(b2) : "v"(b2a));
    asm volatile("s_waitcnt lgkmcnt(0)" ::: "memory");
    __builtin_amdgcn_sched_barrier(0);
    AU ua0, ua1;
    ua0.u = a0; ua1.u = a1;
    AFrag af;
    af.h[0] = __builtin_amdgcn_cvt_pkrtz(ua0.f[0], ua0.f[1]);
    af.h[1] = __builtin_amdgcn_cvt_pkrtz(ua0.f[2], ua0.f[3]);
    af.h[2] = __builtin_amdgcn_cvt_pkrtz(ua1.f[0], ua1.f[1]);
    af.h[3] = __builtin_amdgcn_cvt_pkrtz(ua1.f[2], ua1.f[3]);
    BU ub0, ub1, ub2;
    ub0.u = b0; ub1.u = b1; ub2.u = b2;
    acc[0] = __builtin_amdgcn_mfma_f32_16x16x32_f16(af.v, ub0.v, acc[0], 0, 0, 0);
    acc[1] = __builtin_amdgcn_mfma_f32_16x16x32_f16(af.v, ub1.v, acc[1], 0, 0, 0);
    acc[2] = __builtin_amdgcn_mfma_f32_16x16x32_f16(af.v, ub2.v, acc[2], 0, 0, 0);
}

__global__ __launch_bounds__(THREADS)
void pathnet_kernel(const float* __restrict__ x, const char* __restrict__ ws,
                    const int* __restrict__ pathway, float* __restrict__ out)
{
    __shared__ __align__(16) char smem[45056];

    const int t    = threadIdx.x;
    const int lane = t & 63;
    const int w    = __builtin_amdgcn_readfirstlane(t >> 6);
    const bool wlt3 = (w < 3);

    bool is64 = ((pathway[1] | pathway[3] | pathway[5] | pathway[7]) == 0);
    int e10, e11, e20, e21, e30, e31;
    float m1, m2, m3;
    route(pathway, is64, 0, e10, e11, m1);
    route(pathway, is64, 1, e20, e21, m2);
    route(pathway, is64, 2, e30, e31, m3);

    const _Float16* Whc = (const _Float16*)(ws + OFF_WHC);
    const int sbase0 = blockIdx.x * SPB;
    const float* xg = x + (size_t)sbase0 * IN_DIM;

    const int row16 = lane & 15;
    const int kg    = lane >> 4;
    const int arow  = w * 16 + row16;
    const int aoff0 = arow * 128 + (((2 * kg + 0) ^ (arow & 7)) * 16);
    const int aoff1 = arow * 128 + (((2 * kg + 1) ^ (arow & 7)) * 16);
    int boff[3];
#pragma unroll
    for (int tt = 0; tt < 3; ++tt) {
        const int u = tt * 16 + row16;
        boff[tt] = 32768 + u * 64 + ((kg ^ ((u >> 1) & 3)) * 16);
    }

    f32x4 acc[3];
#pragma unroll
    for (int tt = 0; tt < 3; ++tt) acc[tt] = (f32x4){0.f, 0.f, 0.f, 0.f};

    // ---- prologue + main staged loop (r14-proven) ----
    stageA(smem, 0, 0, xg, w, lane);  stageB(smem, 0, 0, Whc, w, lane);
    stageA(smem, 1, 1, xg, w, lane);  stageB(smem, 1, 1, Whc, w, lane);

#pragma unroll
    for (int i = 0; i < NFULL; ++i) {
        if (i + 2 < NFULL) {
            stageA(smem, (i + 2) & 3, i + 2, xg, w, lane);
            stageB(smem, (i + 2) & 3, i + 2, Whc, w, lane);
        }
        if (i < NFULL - 2)       { if (wlt3) WAITVM(6); else WAITVM(4); }
        else if (i == NFULL - 2) { if (wlt3) WAITVM(3); else WAITVM(2); }
        else                     { WAITVM(0); }
        __builtin_amdgcn_s_barrier();
        asm volatile("" ::: "memory");
        const int bb = (i & 3);
        computeAsm(aoff0 + bb * 8192, aoff1 + bb * 8192,
                   boff[0] + bb * 3072, boff[1] + bb * 3072, boff[2] + bb * 3072,
                   acc);
    }

    // ---- direct tail: k in [768, 784) ----
    {
        AFrag af;
        BFrag bf[3];
        if (kg < 2) {
            const float* ap = xg + (size_t)(w * 16 + row16) * IN_DIM + 768 + kg * 8;
            const float4 q0 = *reinterpret_cast<const float4*>(ap);
            const float4 q1 = *reinterpret_cast<const float4*>(ap + 4);
            af.h[0] = __builtin_amdgcn_cvt_pkrtz(q0.x, q0.y);
            af.h[1] = __builtin_amdgcn_cvt_pkrtz(q0.z, q0.w);
            af.h[2] = __builtin_amdgcn_cvt_pkrtz(q1.x, q1.y);
            af.h[3] = __builtin_amdgcn_cvt_pkrtz(q1.z, q1.w);
#pragma unroll
            for (int tt = 0; tt < 3; ++tt) {
                const int u = tt * 16 + row16;
                bf[tt].q = *reinterpret_cast<const uint4*>(Whc + (size_t)u * IN_DIM + 768 + kg * 8);
            }
        } else {
            const fp16x2 z = __builtin_amdgcn_cvt_pkrtz(0.f, 0.f);
            af.h[0] = af.h[1] = af.h[2] = af.h[3] = z;
#pragma unroll
            for (int tt = 0; tt < 3; ++tt) bf[tt].q = make_uint4(0, 0, 0, 0);
        }
#pragma unroll
        for (int tt = 0; tt < 3; ++tt)
            acc[tt] = __builtin_amdgcn_mfma_f32_16x16x32_f16(af.v, bf[tt].v, acc[tt], 0, 0, 0);
    }

    // ================= MFMA epilogue (per-wave private) =================
    float* pre = reinterpret_cast<float*>(smem) + w * (16 * 44);

#pragma unroll
    for (int tt = 0; tt < 3; ++tt) {
        const int col = tt * 16 + row16;
        if (col < 2 * HDIM) {
#pragma unroll
            for (int r = 0; r < 4; ++r)
                pre[(kg * 4 + r) * 44 + col] = acc[tt][r];
        }
    }

    const _Float16* W2c = (const _Float16*)(ws + OFF_W2C);
    const _Float16* W3c = (const _Float16*)(ws + OFF_W3C);
    const _Float16* Wlc = (const _Float16*)(ws + OFF_WLC);
    const float*    bc  = (const float*)(ws + OFF_BC);
    const float*    blc = (const float*)(ws + OFF_BLC);

    BFrag w2f[3], w3f[3], wlf;
#pragma unroll
    for (int tt = 0; tt < 3; ++tt) {
        const int u = tt * 16 + row16;
        w2f[tt].q = *reinterpret_cast<const uint4*>(W2c + u * 32 + kg * 8);
        w3f[tt].q = *reinterpret_cast<const uint4*>(W3c + u * 32 + kg * 8);
    }
    wlf.q = *reinterpret_cast<const uint4*>(Wlc + row16 * 32 + kg * 8);
    const float blv = blc[row16];

    const float* prow = pre + row16 * 44;

    auto buildA = [&](const float* b0, const float* b1, float mm) -> AFrag {
        AFrag af;
        if (kg == 3) {
            const fp16x2 z = __builtin_amdgcn_cvt_pkrtz(0.f, 0.f);
            af.h[0] = af.h[1] = af.h[2] = af.h[3] = z;
            return af;
        }
        const float* p = prow + kg * 8;
        const float4 p0 = *reinterpret_cast<const float4*>(p);
        const float4 p1 = *reinterpret_cast<const float4*>(p + 4);
        const float4 q0 = *reinterpret_cast<const float4*>(p + 20);
        const float4 q1 = *reinterpret_cast<const float4*>(p + 24);
        const float4 c0 = *reinterpret_cast<const float4*>(b0 + kg * 8);
        const float4 c1 = *reinterpret_cast<const float4*>(b0 + kg * 8 + 4);
        const float4 d0 = *reinterpret_cast<const float4*>(b1 + kg * 8);
        const float4 d1 = *reinterpret_cast<const float4*>(b1 + kg * 8 + 4);
        float h[8];
        h[0] = fmaxf(p0.x + c0.x, 0.f) + mm * fmaxf(q0.x + d0.x, 0.f);
        h[1] = fmaxf(p0.y + c0.y, 0.f) + mm * fmaxf(q0.y + d0.y, 0.f);
        h[2] = fmaxf(p0.z + c0.z, 0.f) + mm * fmaxf(q0.z + d0.z, 0.f);
        h[3] = fmaxf(p0.w + c0.w, 0.f) + mm * fmaxf(q0.w + d0.w, 0.f);
        h[4] = fmaxf(p1.x + c1.x, 0.f) + mm * fmaxf(q1.x + d1.x, 0.f);
        h[5] = fmaxf(p1.y + c1.y, 0.f) + mm * fmaxf(q1.y + d1.y, 0.f);
        h[6] = fmaxf(p1.z + c1.z, 0.f) + mm * fmaxf(q1.z + d1.z, 0.f);
        h[7] = fmaxf(p1.w + c1.w, 0.f) + mm * fmaxf(q1.w + d1.w, 0.f);
        if (kg == 2) { h[4] = h[5] = h[6] = h[7] = 0.f; }
        af.h[0] = __builtin_amdgcn_cvt_pkrtz(h[0], h[1]);
        af.h[1] = __builtin_amdgcn_cvt_pkrtz(h[2], h[3]);
        af.h[2] = __builtin_amdgcn_cvt_pkrtz(h[4], h[5]);
        af.h[3] = __builtin_amdgcn_cvt_pkrtz(h[6], h[7]);
        return af;
    };

    // layer 2
    AFrag a1 = buildA(bc + 0, bc + 24, m1);
    f32x4 acc2[3];
#pragma unroll
    for (int tt = 0; tt < 3; ++tt) {
        acc2[tt] = (f32x4){0.f, 0.f, 0.f, 0.f};
        acc2[tt] = __builtin_amdgcn_mfma_f32_16x16x32_f16(a1.v, w2f[tt].v, acc2[tt], 0, 0, 0);
    }
#pragma unroll
    for (int tt = 0; tt < 3; ++tt) {
        const int col = tt * 16 + row16;
        if (col < 2 * HDIM) {
#pragma unroll
            for (int r = 0; r < 4; ++r)
                pre[(kg * 4 + r) * 44 + col] = acc2[tt][r];
        }
    }

    // layer 3
    AFrag a2 = buildA(bc + 48, bc + 72, m2);
    f32x4 acc3[3];
#pragma unroll
    for (int tt = 0; tt < 3; ++tt) {
        acc3[tt] = (f32x4){0.f, 0.f, 0.f, 0.f};
        acc3[tt] = __builtin_amdgcn_mfma_f32_16x16x32_f16(a2.v, w3f[tt].v, acc3[tt], 0, 0, 0);
    }
#pragma unroll
    for (int tt = 0; tt < 3; ++tt) {
        const int col = tt * 16 + row16;
        if (col < 2 * HDIM) {
#pragma unroll
            for (int r = 0; r < 4; ++r)
                pre[(kg * 4 + r) * 44 + col] = acc3[tt][r];
        }
    }

    // readout
    AFrag a3 = buildA(bc + 96, bc + 120, m3);
    f32x4 accY = (f32x4){0.f, 0.f, 0.f, 0.f};
    accY = __builtin_amdgcn_mfma_f32_16x16x32_f16(a3.v, wlf.v, accY, 0, 0, 0);

    if (row16 < NCLS) {
#pragma unroll
        for (int r = 0; r < 4; ++r) {
            const int srow = sbase0 + w * SPW + kg * 4 + r;
            out[(size_t)srow * NCLS + row16] = accY[r] + blv;
        }
    }
}

extern "C" void kernel_launch(void* const* d_in, const int* in_sizes, int n_in,
                              void* d_out, int out_size, void* d_ws, size_t ws_size,
                              hipStream_t stream) {
    const float* x  = (const float*)d_in[0];
    const float* W1 = (const float*)d_in[1];
    const float* b1 = (const float*)d_in[2];
    const float* W2 = (const float*)d_in[3];
    const float* b2 = (const float*)d_in[4];
    const float* W3 = (const float*)d_in[5];
    const float* b3 = (const float*)d_in[6];
    const float* Wl = (const float*)d_in[7];
    const float* bl = (const float*)d_in[8];
    const int*   pw = (const int*)d_in[9];
    float* out = (float*)d_out;
    char* ws = (char*)d_ws;

    const int ntask = NWROWS * (IN_DIM / 8) + 3744;   // 8448 tasks, one launch
    cvt_all_kernel<<<(ntask + 255) / 256, 256, 0, stream>>>(
        W1, W2, W3, Wl, b1, b2, b3, bl, pw, ws);

    dim3 grid(BATCH / SPB);   // 1024 blocks x 4 waves
    pathnet_kernel<<<grid, THREADS, 0, stream>>>(x, ws, pw, out);
}